// Round 4
// baseline (561.116 us; speedup 1.0000x reference)
//
#include <hip/hip_runtime.h>
#include <math.h>

#define PI_F 3.14159265358979323846f

__constant__ float c_pkva[12] = {
  -0.0144f, 0.0272f, -0.0526f, 0.0972f, -0.193f, 0.63f,
   0.63f, -0.193f, 0.0972f, -0.0526f, 0.0272f, -0.0144f
};

constexpr int ilog2c(int n) { int l = 0; while (n > 1) { n >>= 1; ++l; } return l; }

// Meyer phi lookup table: [0,1024) for N=1024, [1024,1536) N=512,
// [1536,1792) N=256, [1792,1920) N=128. Filled by phi_init_k each launch.
__device__ float g_phi[1920];
constexpr int phi_off(int N) {
  return (N == 1024) ? 0 : (N == 512) ? 1024 : (N == 256) ? 1536 : 1792;
}

__device__ __forceinline__ float phi_dev(int k, int n) {
  int kk = (k < n - k) ? k : (n - k);
  float w = 2.0f * PI_F * (float)kk / (float)n;
  float s = (w - PI_F / 3.0f) * (3.0f / PI_F);
  s = fminf(fmaxf(s, 0.0f), 1.0f);
  float s2 = s * s;
  float beta = s2 * s2 * (35.0f - 84.0f * s + 70.0f * s2 - 20.0f * s2 * s);
  return __cosf(0.5f * PI_F * beta);
}

__global__ void phi_init_k() {
  int i = blockIdx.x * 256 + threadIdx.x;
  if (i < 1024)      g_phi[i] = phi_dev(i, 1024);
  else if (i < 1536) g_phi[i] = phi_dev(i - 1024, 512);
  else if (i < 1792) g_phi[i] = phi_dev(i - 1536, 256);
  else if (i < 1920) g_phi[i] = phi_dev(i - 1792, 128);
}

__device__ __forceinline__ float2 cmul(float2 a, float2 b) {
  return make_float2(a.x * b.x - a.y * b.y, a.x * b.y + a.y * b.x);
}
__device__ __forceinline__ float2 cadd(float2 a, float2 b) { return make_float2(a.x + b.x, a.y + b.y); }
__device__ __forceinline__ float2 csub(float2 a, float2 b) { return make_float2(a.x - b.x, a.y - b.y); }

// ---------------------------------------------------------------------------
// In-LDS Stockham radix-4 FFT core (unpadded — proven). NT = N/4.
// ---------------------------------------------------------------------------
template <int N>
__device__ __forceinline__ int fft_core4(float2 (*sbuf)[N], float dirsign, int tid, int cur) {
  constexpr int LOG2 = ilog2c(N);
  constexpr int NT = N / 4;
  constexpr bool LEAD2 = (LOG2 & 1);
  if constexpr (LEAD2) {
#pragma unroll
    for (int j = tid; j < N / 2; j += NT) {
      float2 v0 = sbuf[cur][j], v1 = sbuf[cur][j + N / 2];
      float2 e = cadd(v0, v1), o = csub(v0, v1);
      *(float4*)&sbuf[cur ^ 1][2 * j] = make_float4(e.x, e.y, o.x, o.y);
    }
    cur ^= 1;
    __syncthreads();
  }
#pragma unroll
  for (int Ns = LEAD2 ? 2 : 1; Ns < N; Ns <<= 2) {
    int j = tid;
    int base = j & (Ns - 1);
    float ang = dirsign * (2.0f * PI_F) * (float)base / (float)(4 * Ns);
    float2 w1; __sincosf(ang, &w1.y, &w1.x);
    float2 w2 = cmul(w1, w1);
    float2 w3 = cmul(w2, w1);
    float2 v0 = sbuf[cur][j];
    float2 v1 = cmul(sbuf[cur][j + N / 4], w1);
    float2 v2 = cmul(sbuf[cur][j + N / 2], w2);
    float2 v3 = cmul(sbuf[cur][j + 3 * (N / 4)], w3);
    float2 a0 = cadd(v0, v2), a1 = csub(v0, v2);
    float2 a2 = cadd(v1, v3), a3 = csub(v1, v3);
    float2 r1 = make_float2(-dirsign * a3.y, dirsign * a3.x);
    int idxD = ((j - base) << 2) + base;
    cur ^= 1;
    sbuf[cur][idxD]          = cadd(a0, a2);
    sbuf[cur][idxD + Ns]     = cadd(a1, r1);
    sbuf[cur][idxD + 2 * Ns] = csub(a0, a2);
    sbuf[cur][idxD + 3 * Ns] = csub(a1, r1);
    __syncthreads();
  }
  return cur;
}

// ---------------------------------------------------------------------------
// Batched row FFT. LMODE: 1 = complex load, 2 = complex * Hm mask (table).
// SMODE: 0 = complex store, 1 = real store.
// ---------------------------------------------------------------------------
template <int N, int LMODE, int SMODE>
__global__ void __launch_bounds__(N / 4)
fft_rows_k(const void* __restrict__ vin, void* __restrict__ vout,
           float dirsign, float scale) {
  constexpr int NT = N / 4;
  __shared__ __align__(16) float2 sbuf[2][N];
  const int tid = threadIdx.x;
  const int row = blockIdx.x;
  const int r = row & (N - 1);

  if (LMODE == 1) {
    const float2* in = (const float2*)vin;
#pragma unroll
    for (int i = tid; i < N; i += NT) {
      float2 v = in[(size_t)row * N + i];
      sbuf[0][i] = make_float2(v.x * scale, v.y * scale);
    }
  } else {
    const float2* in = (const float2*)vin;
    float pr = g_phi[phi_off(N) + r];
#pragma unroll
    for (int i = tid; i < N; i += NT) {
      float lm = pr * g_phi[phi_off(N) + i];
      float m = sqrtf(fmaxf(1.0f - lm * lm, 0.0f)) * scale;
      float2 v = in[(size_t)row * N + i];
      sbuf[0][i] = make_float2(v.x * m, v.y * m);
    }
  }
  __syncthreads();

  int cur = fft_core4<N>(sbuf, dirsign, tid, 0);

  if (SMODE == 0) {
    float2* outp = (float2*)vout;
#pragma unroll
    for (int i = tid; i < N; i += NT)
      outp[(size_t)row * N + i] = sbuf[cur][i];
  } else {
    float* outp = (float*)vout;
#pragma unroll
    for (int i = tid; i < N; i += NT)
      outp[(size_t)row * N + i] = sbuf[cur][i].x;
  }
}

// ---------------------------------------------------------------------------
// First forward FFT on real input: rows (2r, 2r+1) packed as one complex FFT,
// untangled via Hermitian symmetry. Half-spectrum output (kx in [0, N/2]).
// ---------------------------------------------------------------------------
template <int N, int PITCH>
__global__ void __launch_bounds__(N / 4)
rfft_pairs_half_k(const float* __restrict__ in, float2* __restrict__ out) {
  constexpr int NT = N / 4;
  __shared__ __align__(16) float2 sbuf[2][N];
  const int tid = threadIdx.x;
  const int img = blockIdx.x >> (ilog2c(N) - 1);
  const int r = blockIdx.x & (N / 2 - 1);
  const float* p0 = in + ((size_t)img * N + 2 * r) * N;
  const float* p1 = p0 + N;

#pragma unroll
  for (int i = tid; i < N; i += NT)
    sbuf[0][i] = make_float2(p0[i], p1[i]);
  __syncthreads();

  int cur = fft_core4<N>(sbuf, -1.0f, tid, 0);

  float2* o0 = out + ((size_t)img * N + 2 * r) * PITCH;
  float2* o1 = o0 + PITCH;
#pragma unroll
  for (int i = tid; i <= N / 2; i += NT) {
    float2 Z = sbuf[cur][i];
    float2 Zr = sbuf[cur][(N - i) & (N - 1)];
    float2 Zc = make_float2(Zr.x, -Zr.y);
    o0[i] = make_float2(0.5f * (Z.x + Zc.x), 0.5f * (Z.y + Zc.y));
    float2 dd = make_float2(Z.x - Zc.x, Z.y - Zc.y);
    o1[i] = make_float2(0.5f * dd.y, -0.5f * dd.x);
  }
}

// Rectangular tiled transpose, per-image: in R x C -> out C x R.
__global__ void transpose_rect_k(const float2* __restrict__ in,
                                 float2* __restrict__ out, int R, int C) {
  __shared__ float2 tile[32][33];
  int img = blockIdx.z;
  size_t base = (size_t)img * R * C;
  int c = blockIdx.x * 32 + threadIdx.x;
  int r0 = blockIdx.y * 32;
  for (int j = threadIdx.y; j < 32; j += 8)
    tile[j][threadIdx.x] = in[base + (size_t)(r0 + j) * C + c];
  __syncthreads();
  int r = blockIdx.y * 32 + threadIdx.x;
  int c0 = blockIdx.x * 32;
  for (int j = threadIdx.y; j < 32; j += 8)
    out[base + (size_t)(c0 + j) * R + r] = tile[threadIdx.x][j];
}

// ---------------------------------------------------------------------------
// Level-1 column pass, half spectrum: one block per kx in [0, N/2].
// Fwd FFT along ky, Lm-masked ky-fold to foldb, Hm mask + inverse FFT.
// Output written in 16-row-TILED layout: tout[img][y>>4][kx][y&15]
// (chunk stride PITCH*16) — full-line coalesced stores, and lets the fat
// inverse-row kernel read without a separate transpose pass.
// ---------------------------------------------------------------------------
template <int N, int PITCH>
__global__ void __launch_bounds__(N / 4)
fft_col_half_k(const float2* __restrict__ in, float2* __restrict__ tout,
               float2* __restrict__ foldb) {
  constexpr int NT = N / 4;
  constexpr int NH = N / 2;
  __shared__ __align__(16) float2 sbuf[2][N];
  const int tid = threadIdx.x;
  const int kx = blockIdx.x;   // 0..N/2 inclusive
  const int img = blockIdx.y;
  const float2* rowp = in + ((size_t)img * PITCH + kx) * N;

#pragma unroll
  for (int i = tid; i < N; i += NT)
    sbuf[0][i] = rowp[i];
  __syncthreads();

  int cur = fft_core4<N>(sbuf, -1.0f, tid, 0);

  const float pr = g_phi[phi_off(N) + kx];
  const float inv = 1.0f / (float)N;
  float2* fp = foldb + ((size_t)img * (NH + 1) + kx) * NH;
#pragma unroll
  for (int i = tid; i < NH; i += NT) {
    float2 vA = sbuf[cur][i];
    float2 vB = sbuf[cur][i + NH];
    float lmA = pr * g_phi[phi_off(N) + i];
    float lmB = pr * g_phi[phi_off(N) + i + NH];
    fp[i] = make_float2(0.25f * (vA.x * lmA + vB.x * lmB),
                        0.25f * (vA.y * lmA + vB.y * lmB));
    float hmA = sqrtf(fmaxf(1.0f - lmA * lmA, 0.0f)) * inv;
    float hmB = sqrtf(fmaxf(1.0f - lmB * lmB, 0.0f)) * inv;
    sbuf[cur][i]      = make_float2(vA.x * hmA, vA.y * hmA);
    sbuf[cur][i + NH] = make_float2(vB.x * hmB, vB.y * hmB);
  }
  __syncthreads();

  cur = fft_core4<N>(sbuf, 1.0f, tid, cur);

  const size_t tbase = (size_t)img * ((size_t)PITCH * N) + (size_t)kx * 16;
#pragma unroll
  for (int i = tid; i < N; i += NT)
    tout[tbase + (size_t)(i >> 4) * (PITCH * 16) + (i & 15)] = sbuf[cur][i];
}

// ---------------------------------------------------------------------------
// Fused kx-fold + level-2 alias: block owns spec2 rows rp and rp+256.
// spec2[r][c] = fold[r][c] + conj(fold[512-r][(512-c)&511]); writes both rows
// AND the level-2->3 aliased spec3 row rp directly (saves spec2 re-read).
// ---------------------------------------------------------------------------
__global__ void __launch_bounds__(256)
fold_alias_k(const float2* __restrict__ fold, float2* __restrict__ spec2,
             float2* __restrict__ spec3) {
  __shared__ float2 s2a[512], s2b[512];
  const int rp = blockIdx.x;        // 0..255
  const int img = blockIdx.y;       // 0..15
  const float2* fb = fold + (size_t)img * (513 * 512);
  const float2* fr0 = fb + (size_t)rp * 512;
  const float2* fr1 = fb + (size_t)(512 - rp) * 512;
  const float2* fr2 = fb + (size_t)(rp + 256) * 512;
  const float2* fr3 = fb + (size_t)(256 - rp) * 512;
  float2* sp2 = spec2 + ((size_t)img << 18);
  for (int c = threadIdx.x; c < 512; c += 256) {
    int mc = (512 - c) & 511;
    float2 a0 = fr0[c], b0 = fr1[mc];
    float2 a1 = fr2[c], b1 = fr3[mc];
    float2 v0 = make_float2(a0.x + b0.x, a0.y - b0.y);
    float2 v1 = make_float2(a1.x + b1.x, a1.y - b1.y);
    s2a[c] = v0; s2b[c] = v1;
    sp2[((size_t)rp << 9) + c] = v0;
    sp2[((size_t)(rp + 256) << 9) + c] = v1;
  }
  __syncthreads();
  float pr0 = g_phi[phi_off(512) + rp], pr1 = g_phi[phi_off(512) + rp + 256];
  float2* sp3 = spec3 + ((size_t)img << 16) + ((size_t)rp << 8);
  {
    int c = threadIdx.x;  // 256 threads == 256 cols
    float pc0 = g_phi[phi_off(512) + c], pc1 = g_phi[phi_off(512) + c + 256];
    float2 v00 = s2a[c], v01 = s2a[c + 256], v10 = s2b[c], v11 = s2b[c + 256];
    float m00 = pr0 * pc0, m01 = pr0 * pc1, m10 = pr1 * pc0, m11 = pr1 * pc1;
    sp3[c] = make_float2(
        0.25f * (v00.x * m00 + v01.x * m01 + v10.x * m10 + v11.x * m11),
        0.25f * (v00.y * m00 + v01.y * m01 + v10.y * m10 + v11.y * m11));
  }
}

// ---------------------------------------------------------------------------
// Level-1 FAT fused inverse row FFT + first DFB fan split.
// One block per 16-y chunk of the TILED spectrum (8 row-pairs, sequential).
// Per pair: rows y0=2p' (re) and y0+1 (im) packed into one complex inverse
// FFT from the half-spectrum (conjugate symmetry over kx). Per-pair reads
// touch 16B of each 128B line; the block consumes all 16 y's of every line
// across its 8 pairs -> own-XCD L2 absorbs, HBM reads data exactly once.
// ---------------------------------------------------------------------------
template <int N, int PITCH>
__global__ void __launch_bounds__(N / 4)
ifft_fan_fat_k(const float2* __restrict__ in, float* __restrict__ outb,
               float scale, int halfT) {
  constexpr int NT = N / 4;
  constexpr int W2 = N / 2;
  __shared__ __align__(16) float2 sbuf[2][N];
  const int tid = threadIdx.x;
  const int img = blockIdx.x >> 6;      // 64 chunks per image
  const int Q = blockIdx.x & 63;        // y-chunk (16 rows)
  const size_t ibase = (size_t)img * ((size_t)PITCH * N) + (size_t)Q * (PITCH * 16);

#pragma unroll 1
  for (int p = 0; p < 8; ++p) {
    const int y0 = 16 * Q + 2 * p;
    const int w = 2 * p;
#pragma unroll
    for (int i = tid; i <= W2; i += NT) {
      float2 a = in[ibase + (size_t)i * 16 + w];
      float2 b = in[ibase + (size_t)i * 16 + w + 1];
      sbuf[0][i] = make_float2((a.x - b.y) * scale, (a.y + b.x) * scale);
    }
#pragma unroll
    for (int i = tid; i < W2 - 1; i += NT) {
      int m = W2 - 1 - i;
      float2 a = in[ibase + (size_t)m * 16 + w];
      float2 b = in[ibase + (size_t)m * 16 + w + 1];
      sbuf[0][W2 + 1 + i] = make_float2((a.x + b.y) * scale, (b.x - a.y) * scale);
    }
    __syncthreads();

    int cur = fft_core4<N>(sbuf, 1.0f, tid, 0);

    float* scratch = (float*)sbuf[cur ^ 1];
    float* xe = scratch;            // W2 floats
    float* xo = scratch + W2;       // W2 floats
    float* db = scratch + 2 * W2;   // W2 floats
    const size_t rbase = ((size_t)img * N + y0) * W2;

    for (int sub = 0; sub < 2; ++sub) {
      const int par = sub;                 // y0 even, y1 odd
      const float sgn = par ? -1.0f : 1.0f;
#pragma unroll
      for (int i = tid; i < N; i += NT) {
        float v = par ? sbuf[cur][i].y : sbuf[cur][i].x;
        int ii = (i - par) & (N - 1);
        if (ii & 1) xo[ii >> 1] = v; else xe[ii >> 1] = v;
      }
      __syncthreads();

      float* outs = outb + rbase + (size_t)sub * W2;
      float* outd = outb + halfT + rbase + (size_t)sub * W2;
#pragma unroll 2
      for (int j = tid; j < W2; j += NT) {
        float acc = 0.0f;
#pragma unroll
        for (int k = 0; k < 12; k++)
          acc += c_pkva[k] * xe[(j - 6 + k + W2) & (W2 - 1)];
        float dv = sgn * (xo[j] - acc);
        db[j] = dv;
        outd[j] = dv;
      }
      __syncthreads();
#pragma unroll 2
      for (int j = tid; j < W2; j += NT) {
        float acc = 0.0f;
#pragma unroll
        for (int k = 0; k < 12; k++)
          acc += c_pkva[k] * db[(j - 6 + k + W2) & (W2 - 1)];
        outs[j] = sgn * xe[j] + 0.5f * acc;
      }
      __syncthreads();
    }
  }
}

// ---------------------------------------------------------------------------
// Fused: inverse row FFT + first DFB fan split (axis=-1). Levels 2/3.
// ---------------------------------------------------------------------------
template <int N>
__global__ void __launch_bounds__(N / 4)
ifft_fan_k(const float2* __restrict__ in, float* __restrict__ outb,
           float scale, int halfT) {
  constexpr int NT = N / 4;
  constexpr int W2 = N / 2;
  __shared__ __align__(16) float2 sbuf[2][N];
  const int tid = threadIdx.x;
  const int nr = blockIdx.x;
  const int r = nr & (N - 1);
  const int par = r & 1;
  const float sgn = par ? -1.0f : 1.0f;

#pragma unroll
  for (int i = tid; i < N; i += NT) {
    float2 v = in[(size_t)nr * N + i];
    sbuf[0][i] = make_float2(v.x * scale, v.y * scale);
  }
  __syncthreads();

  int cur = fft_core4<N>(sbuf, 1.0f, tid, 0);

  float* scratch = (float*)sbuf[cur ^ 1];
  float* xe = scratch;
  float* xo = scratch + W2;
  float* db = scratch + 2 * W2;
#pragma unroll
  for (int i = tid; i < N; i += NT) {
    float v = sbuf[cur][i].x;
    int ii = (i - par) & (N - 1);
    if (ii & 1) xo[ii >> 1] = v; else xe[ii >> 1] = v;
  }
  __syncthreads();

  float* outs = outb + (size_t)nr * W2;
  float* outd = outb + halfT + (size_t)nr * W2;
#pragma unroll 2
  for (int j = tid; j < W2; j += NT) {
    float acc = 0.0f;
#pragma unroll
    for (int k = 0; k < 12; k++)
      acc += c_pkva[k] * xe[(j - 6 + k + W2) & (W2 - 1)];
    float dv = sgn * (xo[j] - acc);
    db[j] = dv;
    outd[j] = dv;
  }
  __syncthreads();
#pragma unroll 2
  for (int j = tid; j < W2; j += NT) {
    float acc = 0.0f;
#pragma unroll
    for (int k = 0; k < 12; k++)
      acc += c_pkva[k] * db[(j - 6 + k + W2) & (W2 - 1)];
    outs[j] = sgn * xe[j] + 0.5f * acc;
  }
}

// Batched square transpose (per-image), complex
__global__ void transpose_k(const float2* __restrict__ in,
                            float2* __restrict__ out, int N) {
  __shared__ float2 tile[32][33];
  int img = blockIdx.z;
  size_t base = (size_t)img * N * N;
  int x = blockIdx.x * 32 + threadIdx.x;
  int y0 = blockIdx.y * 32;
  for (int j = threadIdx.y; j < 32; j += 8)
    tile[j][threadIdx.x] = in[base + (size_t)(y0 + j) * N + x];
  __syncthreads();
  int x2 = blockIdx.y * 32 + threadIdx.x;
  int y2 = blockIdx.x * 32;
  for (int j = threadIdx.y; j < 32; j += 8)
    out[base + (size_t)(y2 + j) * N + x2] = tile[threadIdx.x][j];
}

// Frequency-domain decimation by 2 with Lm mask (level 3), table-driven.
__global__ void alias_k(const float2* __restrict__ in, float2* __restrict__ out,
                        int N, int lgN2, int phiOff) {
  int idx = blockIdx.x * 256 + threadIdx.x;
  int N2 = N >> 1;
  int c = idx & (N2 - 1);
  int r = (idx >> lgN2) & (N2 - 1);
  int img = idx >> (2 * lgN2);
  float pr0 = g_phi[phiOff + r], pr1 = g_phi[phiOff + r + N2];
  float pc0 = g_phi[phiOff + c], pc1 = g_phi[phiOff + c + N2];
  size_t base = (size_t)img * N * N;
  float2 v00 = in[base + (size_t)r * N + c];
  float2 v01 = in[base + (size_t)r * N + c + N2];
  float2 v10 = in[base + (size_t)(r + N2) * N + c];
  float2 v11 = in[base + (size_t)(r + N2) * N + c + N2];
  float m00 = pr0 * pc0, m01 = pr0 * pc1, m10 = pr1 * pc0, m11 = pr1 * pc1;
  float2 o;
  o.x = 0.25f * (v00.x * m00 + v01.x * m01 + v10.x * m10 + v11.x * m11);
  o.y = 0.25f * (v00.y * m00 + v01.y * m01 + v10.y * m10 + v11.y * m11);
  out[((size_t)img << (2 * lgN2)) + ((size_t)r << lgN2) + c] = o;
}

// Standalone DFB fan split, axis=-1 (mid-pipeline; W <= 512 here).
__global__ void __launch_bounds__(256)
fs_row_k(const float* __restrict__ x, float* __restrict__ outb,
         int lgH, int lgW, int halfT) {
  __shared__ float xe[512], xo[512], db[512];
  int H = 1 << lgH, W = 1 << lgW, W2 = W >> 1;
  int nr = blockIdx.x;
  int r = nr & (H - 1);
  int par = r & 1;
  float sgn = par ? -1.0f : 1.0f;
  const float* xrow = x + (size_t)nr * W;
  for (int j = threadIdx.x; j < W2; j += 256) {
    xe[j] = sgn * xrow[(2 * j + par) & (W - 1)];
    xo[j] = sgn * xrow[(2 * j + 1 + par) & (W - 1)];
  }
  __syncthreads();
  float* outs = outb + (size_t)nr * W2;
  float* outd = outb + halfT + (size_t)nr * W2;
  for (int j = threadIdx.x; j < W2; j += 256) {
    float acc = 0.0f;
#pragma unroll
    for (int k = 0; k < 12; k++)
      acc += c_pkva[k] * xe[(j - 6 + k + W2) & (W2 - 1)];
    float dv = xo[j] - acc;
    db[j] = dv;
    outd[j] = dv;
  }
  __syncthreads();
  for (int j = threadIdx.x; j < W2; j += 256) {
    float acc = 0.0f;
#pragma unroll
    for (int k = 0; k < 12; k++)
      acc += c_pkva[k] * db[(j - 6 + k + W2) & (W2 - 1)];
    outs[j] = xe[j] + 0.5f * acc;
  }
}

// ---------------------------------------------------------------------------
// FUSED column fan split (d AND s in one pass, input read once).
// ---------------------------------------------------------------------------
template <int TI, int TC>
__global__ void __launch_bounds__(256)
fs_col_fused_k(const float* __restrict__ x, float* __restrict__ outb,
               int lgH, int lgW, int halfT) {
  constexpr int RE = 2 * TI + 48;
  constexpr int DE = TI + 12;
  constexpr int NR = 256 / TC;
  __shared__ float raw[RE][TC];
  __shared__ float dvs[DE][TC];
  const int H = 1 << lgH, W = 1 << lgW;
  const int c0 = blockIdx.x * TC;
  const int i0 = blockIdx.y * TI;
  const int n = blockIdx.z;
  const int tc = threadIdx.x & (TC - 1);
  const int tr = threadIdx.x / TC;
  const float* xim = x + ((size_t)n << (lgH + lgW));
  const int rbase = 2 * i0 - 24;
#pragma unroll
  for (int r = tr; r < RE; r += NR) {
    int rr = (rbase + r) & (H - 1);
    raw[r][tc] = xim[((size_t)rr << lgW) + c0 + tc];
  }
  __syncthreads();
  const int par = tc & 1;
  for (int j = tr; j < DE; j += NR) {
    float acc = 0.0f;
#pragma unroll
    for (int k = 0; k < 12; k++)
      acc += c_pkva[k] * raw[2 * j + 2 * k + par][tc];
    dvs[j][tc] = raw[2 * j + 13 + par][tc] - acc;
  }
  __syncthreads();
  const float sgn = par ? -1.0f : 1.0f;
  float* outs = outb + (((size_t)n << (lgH - 1)) << lgW);
  float* outd = outs + halfT;
  for (int i = tr; i < TI; i += NR) {
    float acc = 0.0f;
#pragma unroll
    for (int k = 0; k < 12; k++)
      acc += c_pkva[k] * dvs[i + k][tc];
    float p0v = raw[2 * i + 24 + par][tc];
    size_t off = ((size_t)(i0 + i) << lgW) + c0 + tc;
    outd[off] = sgn * dvs[i + 6][tc];
    outs[off] = sgn * (p0v + 0.5f * acc);
  }
}

__global__ void fill_err_k(float* out) {
  out[threadIdx.x] = 1.0e9f;
}

// ---------------------------------------------------------------------------
extern "C" void kernel_launch(void* const* d_in, const int* in_sizes, int n_in,
                              void* d_out, int out_size, void* d_ws, size_t ws_size,
                              hipStream_t stream) {
  const float* x = (const float*)d_in[0];
  float* out = (float*)d_out;
  char* ws = (char*)d_ws;

  const size_t NEED = 220266496ull;
  if (ws_size < NEED) {
    fill_err_k<<<dim3(1), dim3(256), 0, stream>>>(out);
    return;
  }

  float2* bufA  = (float2*)(ws);                 // 16*1024*544*8 = 71303168
  float2* bufB  = (float2*)(ws + 71303168);      // 71303168
  float2* foldb = (float2*)(ws + 142606336);     // 16*513*512*8 = 33619968
  float2* spec2 = (float2*)(ws + 176226304);     // 33554432
  float2* spec3 = (float2*)(ws + 209780736);     // 8388608
  float2* spec4 = (float2*)(ws + 218169344);     // 2097152

  float* out0 = out;             // 262144
  float* out1 = out + 262144;    // 1048576
  float* out2 = out + 1310720;   // 4194304
  float* out3 = out + 5505024;   // 16777216

  phi_init_k<<<dim3(8), dim3(256), 0, stream>>>();

  // ---- Level 1 (half-spectrum in kx)
  rfft_pairs_half_k<1024, 544><<<dim3(8192), dim3(256), 0, stream>>>(x, bufA);
  // bufA [img][y][kx<=512] -> bufB [img][kx][y]
  transpose_rect_k<<<dim3(17, 32, 16), dim3(32, 8), 0, stream>>>(bufA, bufB, 1024, 544);
  // col FFT + ky-fold; Hm*inverse written TILED into bufA (replaces transpose2)
  fft_col_half_k<1024, 544><<<dim3(513, 16), dim3(256), 0, stream>>>(bufB, bufA, foldb);
  // kx-fold -> spec2 AND level-2 alias -> spec3 in one pass
  fold_alias_k<<<dim3(256, 16), dim3(256), 0, stream>>>(foldb, spec2, spec3);
  // fat inverse-row + fan split reads tiled bufA directly
  ifft_fan_fat_k<1024, 544><<<dim3(1024), dim3(256), 0, stream>>>(bufA, (float*)bufB, 1.0f / 1024.0f, 8388608);
  // DFB n=4 remaining stages (fused column splits)
  fs_col_fused_k<64, 32><<<dim3(16, 8, 32), dim3(256), 0, stream>>>((float*)bufB, (float*)bufA, 10, 9, 8388608);
  fs_row_k<<<dim3(32768), dim3(256), 0, stream>>>((float*)bufA, (float*)bufB, 9, 9, 8388608);
  fs_col_fused_k<64, 32><<<dim3(8, 4, 128), dim3(256), 0, stream>>>((float*)bufB, out3, 9, 8, 8388608);

  // ---- Level 2 (spec3 already produced by fold_alias_k)
  fft_rows_k<512, 2, 0><<<dim3(8192), dim3(128), 0, stream>>>((const void*)spec2, (void*)bufA, 1.0f, 1.0f / 512.0f);
  transpose_k<<<dim3(16, 16, 16), dim3(32, 8), 0, stream>>>(bufA, bufB, 512);
  ifft_fan_k<512><<<dim3(8192), dim3(128), 0, stream>>>(bufB, (float*)bufA, 1.0f / 512.0f, 2097152);
  fs_col_fused_k<64, 32><<<dim3(8, 4, 32), dim3(256), 0, stream>>>((float*)bufA, (float*)bufB, 9, 8, 2097152);
  fs_row_k<<<dim3(16384), dim3(256), 0, stream>>>((float*)bufB, out2, 8, 8, 2097152);

  // ---- Level 3
  alias_k<<<dim3(1024), dim3(256), 0, stream>>>(spec3, spec4, 256, 7, phi_off(256));
  fft_rows_k<256, 2, 0><<<dim3(4096), dim3(64), 0, stream>>>((const void*)spec3, (void*)bufA, 1.0f, 1.0f / 256.0f);
  transpose_k<<<dim3(8, 8, 16), dim3(32, 8), 0, stream>>>(bufA, bufB, 256);
  ifft_fan_k<256><<<dim3(4096), dim3(64), 0, stream>>>(bufB, (float*)bufA, 1.0f / 256.0f, 524288);
  fs_col_fused_k<64, 32><<<dim3(4, 2, 32), dim3(256), 0, stream>>>((float*)bufA, out1, 8, 7, 524288);

  // ---- Final lowpass: out0 = ifft2(X4^T) at 128^2
  fft_rows_k<128, 1, 0><<<dim3(2048), dim3(32), 0, stream>>>((const void*)spec4, (void*)bufA, 1.0f, 1.0f / 128.0f);
  transpose_k<<<dim3(4, 4, 16), dim3(32, 8), 0, stream>>>(bufA, bufB, 128);
  fft_rows_k<128, 1, 1><<<dim3(2048), dim3(32), 0, stream>>>((const void*)bufB, (void*)out0, 1.0f, 1.0f / 128.0f);
}

// Round 5
// 479.080 us; speedup vs baseline: 1.1712x; 1.1712x over previous
//
#include <hip/hip_runtime.h>
#include <math.h>

#define PI_F 3.14159265358979323846f

__constant__ float c_pkva[12] = {
  -0.0144f, 0.0272f, -0.0526f, 0.0972f, -0.193f, 0.63f,
   0.63f, -0.193f, 0.0972f, -0.0526f, 0.0272f, -0.0144f
};

constexpr int ilog2c(int n) { int l = 0; while (n > 1) { n >>= 1; ++l; } return l; }

// Meyer phi lookup table: [0,1024) for N=1024, [1024,1536) N=512,
// [1536,1792) N=256, [1792,1920) N=128. Filled by phi_init_k each launch.
__device__ float g_phi[1920];
constexpr int phi_off(int N) {
  return (N == 1024) ? 0 : (N == 512) ? 1024 : (N == 256) ? 1536 : 1792;
}

__device__ __forceinline__ float phi_dev(int k, int n) {
  int kk = (k < n - k) ? k : (n - k);
  float w = 2.0f * PI_F * (float)kk / (float)n;
  float s = (w - PI_F / 3.0f) * (3.0f / PI_F);
  s = fminf(fmaxf(s, 0.0f), 1.0f);
  float s2 = s * s;
  float beta = s2 * s2 * (35.0f - 84.0f * s + 70.0f * s2 - 20.0f * s2 * s);
  return __cosf(0.5f * PI_F * beta);
}

__global__ void phi_init_k() {
  int i = blockIdx.x * 256 + threadIdx.x;
  if (i < 1024)      g_phi[i] = phi_dev(i, 1024);
  else if (i < 1536) g_phi[i] = phi_dev(i - 1024, 512);
  else if (i < 1792) g_phi[i] = phi_dev(i - 1536, 256);
  else if (i < 1920) g_phi[i] = phi_dev(i - 1792, 128);
}

__device__ __forceinline__ float2 cmul(float2 a, float2 b) {
  return make_float2(a.x * b.x - a.y * b.y, a.x * b.y + a.y * b.x);
}
__device__ __forceinline__ float2 cadd(float2 a, float2 b) { return make_float2(a.x + b.x, a.y + b.y); }
__device__ __forceinline__ float2 csub(float2 a, float2 b) { return make_float2(a.x - b.x, a.y - b.y); }

// ---------------------------------------------------------------------------
// In-LDS Stockham radix-4 FFT core (unpadded — proven). NT = N/4.
// ---------------------------------------------------------------------------
template <int N>
__device__ __forceinline__ int fft_core4(float2 (*sbuf)[N], float dirsign, int tid, int cur) {
  constexpr int LOG2 = ilog2c(N);
  constexpr int NT = N / 4;
  constexpr bool LEAD2 = (LOG2 & 1);
  if constexpr (LEAD2) {
#pragma unroll
    for (int j = tid; j < N / 2; j += NT) {
      float2 v0 = sbuf[cur][j], v1 = sbuf[cur][j + N / 2];
      float2 e = cadd(v0, v1), o = csub(v0, v1);
      *(float4*)&sbuf[cur ^ 1][2 * j] = make_float4(e.x, e.y, o.x, o.y);
    }
    cur ^= 1;
    __syncthreads();
  }
#pragma unroll
  for (int Ns = LEAD2 ? 2 : 1; Ns < N; Ns <<= 2) {
    int j = tid;
    int base = j & (Ns - 1);
    float ang = dirsign * (2.0f * PI_F) * (float)base / (float)(4 * Ns);
    float2 w1; __sincosf(ang, &w1.y, &w1.x);
    float2 w2 = cmul(w1, w1);
    float2 w3 = cmul(w2, w1);
    float2 v0 = sbuf[cur][j];
    float2 v1 = cmul(sbuf[cur][j + N / 4], w1);
    float2 v2 = cmul(sbuf[cur][j + N / 2], w2);
    float2 v3 = cmul(sbuf[cur][j + 3 * (N / 4)], w3);
    float2 a0 = cadd(v0, v2), a1 = csub(v0, v2);
    float2 a2 = cadd(v1, v3), a3 = csub(v1, v3);
    float2 r1 = make_float2(-dirsign * a3.y, dirsign * a3.x);
    int idxD = ((j - base) << 2) + base;
    cur ^= 1;
    sbuf[cur][idxD]          = cadd(a0, a2);
    sbuf[cur][idxD + Ns]     = cadd(a1, r1);
    sbuf[cur][idxD + 2 * Ns] = csub(a0, a2);
    sbuf[cur][idxD + 3 * Ns] = csub(a1, r1);
    __syncthreads();
  }
  return cur;
}

// ---------------------------------------------------------------------------
// Batched row FFT. LMODE: 1 = complex load, 2 = complex * Hm mask (table).
// SMODE: 0 = complex store, 1 = real store.
// ---------------------------------------------------------------------------
template <int N, int LMODE, int SMODE>
__global__ void __launch_bounds__(N / 4)
fft_rows_k(const void* __restrict__ vin, void* __restrict__ vout,
           float dirsign, float scale) {
  constexpr int NT = N / 4;
  __shared__ __align__(16) float2 sbuf[2][N];
  const int tid = threadIdx.x;
  const int row = blockIdx.x;
  const int r = row & (N - 1);

  if (LMODE == 1) {
    const float2* in = (const float2*)vin;
#pragma unroll
    for (int i = tid; i < N; i += NT) {
      float2 v = in[(size_t)row * N + i];
      sbuf[0][i] = make_float2(v.x * scale, v.y * scale);
    }
  } else {
    const float2* in = (const float2*)vin;
    float pr = g_phi[phi_off(N) + r];
#pragma unroll
    for (int i = tid; i < N; i += NT) {
      float lm = pr * g_phi[phi_off(N) + i];
      float m = sqrtf(fmaxf(1.0f - lm * lm, 0.0f)) * scale;
      float2 v = in[(size_t)row * N + i];
      sbuf[0][i] = make_float2(v.x * m, v.y * m);
    }
  }
  __syncthreads();

  int cur = fft_core4<N>(sbuf, dirsign, tid, 0);

  if (SMODE == 0) {
    float2* outp = (float2*)vout;
#pragma unroll
    for (int i = tid; i < N; i += NT)
      outp[(size_t)row * N + i] = sbuf[cur][i];
  } else {
    float* outp = (float*)vout;
#pragma unroll
    for (int i = tid; i < N; i += NT)
      outp[(size_t)row * N + i] = sbuf[cur][i].x;
  }
}

// ---------------------------------------------------------------------------
// First forward FFT on real input, COLUMN-MAJOR half-spectrum output:
// rows (2r, 2r+1) packed as one complex FFT, untangled via Hermitian
// symmetry, stored directly as out[img][kx][y] (kills transpose #1).
// (o0,o1) for y=2r,2r+1 are adjacent -> one float4 store (16 B granule at
// 8 KB stride). XCD swizzle r = (b&7)*64 + (b>>3): since bid%8 == b%8, each
// XCD owns a contiguous 64-r chunk, so all 8 writers of a 128 B line are on
// the same XCD L2 (dirty set ~0.5 MB << 4 MB) -> full-line writebacks.
// ---------------------------------------------------------------------------
template <int N, int PITCH>
__global__ void __launch_bounds__(N / 4)
rfft_pairs_cm_k(const float* __restrict__ in, float2* __restrict__ out) {
  constexpr int NT = N / 4;
  __shared__ __align__(16) float2 sbuf[2][N];
  const int tid = threadIdx.x;
  const int img = blockIdx.x >> (ilog2c(N) - 1);
  const int b = blockIdx.x & (N / 2 - 1);
  const int r = ((b & 7) << (ilog2c(N) - 4)) + (b >> 3);  // chunk = N/16
  const float* p0 = in + ((size_t)img * N + 2 * r) * N;
  const float* p1 = p0 + N;

#pragma unroll
  for (int i = tid; i < N; i += NT)
    sbuf[0][i] = make_float2(p0[i], p1[i]);
  __syncthreads();

  int cur = fft_core4<N>(sbuf, -1.0f, tid, 0);

  float2* ob = out + (size_t)img * ((size_t)PITCH * N) + 2 * r;
#pragma unroll
  for (int i = tid; i <= N / 2; i += NT) {
    float2 Z = sbuf[cur][i];
    float2 Zr = sbuf[cur][(N - i) & (N - 1)];
    float2 Zc = make_float2(Zr.x, -Zr.y);
    float2 o0 = make_float2(0.5f * (Z.x + Zc.x), 0.5f * (Z.y + Zc.y));
    float2 dd = make_float2(Z.x - Zc.x, Z.y - Zc.y);
    float2 o1 = make_float2(0.5f * dd.y, -0.5f * dd.x);
    *(float4*)&ob[(size_t)i * N] = make_float4(o0.x, o0.y, o1.x, o1.y);
  }
}

// Rectangular tiled transpose, per-image: in R x C -> out C x R.
__global__ void transpose_rect_k(const float2* __restrict__ in,
                                 float2* __restrict__ out, int R, int C) {
  __shared__ float2 tile[32][33];
  int img = blockIdx.z;
  size_t base = (size_t)img * R * C;
  int c = blockIdx.x * 32 + threadIdx.x;
  int r0 = blockIdx.y * 32;
  for (int j = threadIdx.y; j < 32; j += 8)
    tile[j][threadIdx.x] = in[base + (size_t)(r0 + j) * C + c];
  __syncthreads();
  int r = blockIdx.y * 32 + threadIdx.x;
  int c0 = blockIdx.x * 32;
  for (int j = threadIdx.y; j < 32; j += 8)
    out[base + (size_t)(c0 + j) * R + r] = tile[threadIdx.x][j];
}

// ---------------------------------------------------------------------------
// Level-1 column pass, half spectrum: one block per kx in [0, N/2].
// Fwd FFT along ky, Lm-masked ky-fold to foldb, Hm mask + inverse FFT,
// stored in place (row kx of the column-major buffer).
// ---------------------------------------------------------------------------
template <int N, int PITCH>
__global__ void __launch_bounds__(N / 4)
fft_col_half_k(float2* __restrict__ inout, float2* __restrict__ foldb) {
  constexpr int NT = N / 4;
  constexpr int NH = N / 2;
  __shared__ __align__(16) float2 sbuf[2][N];
  const int tid = threadIdx.x;
  const int kx = blockIdx.x;   // 0..N/2 inclusive
  const int img = blockIdx.y;
  float2* rowp = inout + ((size_t)img * PITCH + kx) * N;

#pragma unroll
  for (int i = tid; i < N; i += NT)
    sbuf[0][i] = rowp[i];
  __syncthreads();

  int cur = fft_core4<N>(sbuf, -1.0f, tid, 0);

  const float pr = g_phi[phi_off(N) + kx];
  const float inv = 1.0f / (float)N;
  float2* fp = foldb + ((size_t)img * (NH + 1) + kx) * NH;
#pragma unroll
  for (int i = tid; i < NH; i += NT) {
    float2 vA = sbuf[cur][i];
    float2 vB = sbuf[cur][i + NH];
    float lmA = pr * g_phi[phi_off(N) + i];
    float lmB = pr * g_phi[phi_off(N) + i + NH];
    fp[i] = make_float2(0.25f * (vA.x * lmA + vB.x * lmB),
                        0.25f * (vA.y * lmA + vB.y * lmB));
    float hmA = sqrtf(fmaxf(1.0f - lmA * lmA, 0.0f)) * inv;
    float hmB = sqrtf(fmaxf(1.0f - lmB * lmB, 0.0f)) * inv;
    sbuf[cur][i]      = make_float2(vA.x * hmA, vA.y * hmA);
    sbuf[cur][i + NH] = make_float2(vB.x * hmB, vB.y * hmB);
  }
  __syncthreads();

  cur = fft_core4<N>(sbuf, 1.0f, tid, cur);

#pragma unroll
  for (int i = tid; i < N; i += NT)
    rowp[i] = sbuf[cur][i];
}

// ---------------------------------------------------------------------------
// Fused kx-fold + level-2 alias: block owns spec2 rows rp and rp+256.
// spec2[r][c] = fold[r][c] + conj(fold[512-r][(512-c)&511]); writes both rows
// AND the level-2->3 aliased spec3 row rp directly (saves spec2 re-read).
// ---------------------------------------------------------------------------
__global__ void __launch_bounds__(256)
fold_alias_k(const float2* __restrict__ fold, float2* __restrict__ spec2,
             float2* __restrict__ spec3) {
  __shared__ float2 s2a[512], s2b[512];
  const int rp = blockIdx.x;        // 0..255
  const int img = blockIdx.y;       // 0..15
  const float2* fb = fold + (size_t)img * (513 * 512);
  const float2* fr0 = fb + (size_t)rp * 512;
  const float2* fr1 = fb + (size_t)(512 - rp) * 512;
  const float2* fr2 = fb + (size_t)(rp + 256) * 512;
  const float2* fr3 = fb + (size_t)(256 - rp) * 512;
  float2* sp2 = spec2 + ((size_t)img << 18);
  for (int c = threadIdx.x; c < 512; c += 256) {
    int mc = (512 - c) & 511;
    float2 a0 = fr0[c], b0 = fr1[mc];
    float2 a1 = fr2[c], b1 = fr3[mc];
    float2 v0 = make_float2(a0.x + b0.x, a0.y - b0.y);
    float2 v1 = make_float2(a1.x + b1.x, a1.y - b1.y);
    s2a[c] = v0; s2b[c] = v1;
    sp2[((size_t)rp << 9) + c] = v0;
    sp2[((size_t)(rp + 256) << 9) + c] = v1;
  }
  __syncthreads();
  float pr0 = g_phi[phi_off(512) + rp], pr1 = g_phi[phi_off(512) + rp + 256];
  float2* sp3 = spec3 + ((size_t)img << 16) + ((size_t)rp << 8);
  {
    int c = threadIdx.x;  // 256 threads == 256 cols
    float pc0 = g_phi[phi_off(512) + c], pc1 = g_phi[phi_off(512) + c + 256];
    float2 v00 = s2a[c], v01 = s2a[c + 256], v10 = s2b[c], v11 = s2b[c + 256];
    float m00 = pr0 * pc0, m01 = pr0 * pc1, m10 = pr1 * pc0, m11 = pr1 * pc1;
    sp3[c] = make_float2(
        0.25f * (v00.x * m00 + v01.x * m01 + v10.x * m10 + v11.x * m11),
        0.25f * (v00.y * m00 + v01.y * m01 + v10.y * m10 + v11.y * m11));
  }
}

// ---------------------------------------------------------------------------
// Level-1 fused inverse row FFT + first DFB fan split, TWO ROWS PER BLOCK:
// rows of Z over kx are conjugate-symmetric, so rows y0=2q (re) and y1=2q+1
// (im) are packed into one complex inverse FFT from the stored half-spectrum.
// ---------------------------------------------------------------------------
template <int N, int PITCH>
__global__ void __launch_bounds__(N / 4)
ifft_fan_pair_k(const float2* __restrict__ in, float* __restrict__ outb,
                float scale, int halfT) {
  constexpr int NT = N / 4;
  constexpr int W2 = N / 2;
  __shared__ __align__(16) float2 sbuf[2][N];
  const int tid = threadIdx.x;
  const int img = blockIdx.x >> (ilog2c(N) - 1);
  const int q = blockIdx.x & (N / 2 - 1);
  const int y0 = 2 * q;
  const float2* inA = in + ((size_t)img * N + y0) * PITCH;
  const float2* inB = inA + PITCH;

#pragma unroll
  for (int i = tid; i <= W2; i += NT) {
    float2 a = inA[i], b = inB[i];
    sbuf[0][i] = make_float2((a.x - b.y) * scale, (a.y + b.x) * scale);
  }
#pragma unroll
  for (int i = tid; i < W2 - 1; i += NT) {
    int m = W2 - 1 - i;                  // source index: 511..1
    float2 a = inA[m], b = inB[m];
    sbuf[0][W2 + 1 + i] = make_float2((a.x + b.y) * scale, (b.x - a.y) * scale);
  }
  __syncthreads();

  int cur = fft_core4<N>(sbuf, 1.0f, tid, 0);

  float* scratch = (float*)sbuf[cur ^ 1];
  float* xe = scratch;            // W2 floats
  float* xo = scratch + W2;       // W2 floats
  float* db = scratch + 2 * W2;   // W2 floats
  const size_t rbase = ((size_t)img * N + y0) * W2;

  for (int sub = 0; sub < 2; ++sub) {
    const int par = sub;                 // y0 even, y1 odd
    const float sgn = par ? -1.0f : 1.0f;
#pragma unroll
    for (int i = tid; i < N; i += NT) {
      float v = par ? sbuf[cur][i].y : sbuf[cur][i].x;
      int ii = (i - par) & (N - 1);
      if (ii & 1) xo[ii >> 1] = v; else xe[ii >> 1] = v;
    }
    __syncthreads();

    float* outs = outb + rbase + (size_t)sub * W2;
    float* outd = outb + halfT + rbase + (size_t)sub * W2;
#pragma unroll 2
    for (int j = tid; j < W2; j += NT) {
      float acc = 0.0f;
#pragma unroll
      for (int k = 0; k < 12; k++)
        acc += c_pkva[k] * xe[(j - 6 + k + W2) & (W2 - 1)];
      float dv = sgn * (xo[j] - acc);
      db[j] = dv;
      outd[j] = dv;
    }
    __syncthreads();
#pragma unroll 2
    for (int j = tid; j < W2; j += NT) {
      float acc = 0.0f;
#pragma unroll
      for (int k = 0; k < 12; k++)
        acc += c_pkva[k] * db[(j - 6 + k + W2) & (W2 - 1)];
      outs[j] = sgn * xe[j] + 0.5f * acc;
    }
    __syncthreads();
  }
}

// ---------------------------------------------------------------------------
// Fused: inverse row FFT + first DFB fan split (axis=-1). Levels 2/3.
// ---------------------------------------------------------------------------
template <int N>
__global__ void __launch_bounds__(N / 4)
ifft_fan_k(const float2* __restrict__ in, float* __restrict__ outb,
           float scale, int halfT) {
  constexpr int NT = N / 4;
  constexpr int W2 = N / 2;
  __shared__ __align__(16) float2 sbuf[2][N];
  const int tid = threadIdx.x;
  const int nr = blockIdx.x;
  const int r = nr & (N - 1);
  const int par = r & 1;
  const float sgn = par ? -1.0f : 1.0f;

#pragma unroll
  for (int i = tid; i < N; i += NT) {
    float2 v = in[(size_t)nr * N + i];
    sbuf[0][i] = make_float2(v.x * scale, v.y * scale);
  }
  __syncthreads();

  int cur = fft_core4<N>(sbuf, 1.0f, tid, 0);

  float* scratch = (float*)sbuf[cur ^ 1];
  float* xe = scratch;
  float* xo = scratch + W2;
  float* db = scratch + 2 * W2;
#pragma unroll
  for (int i = tid; i < N; i += NT) {
    float v = sbuf[cur][i].x;
    int ii = (i - par) & (N - 1);
    if (ii & 1) xo[ii >> 1] = v; else xe[ii >> 1] = v;
  }
  __syncthreads();

  float* outs = outb + (size_t)nr * W2;
  float* outd = outb + halfT + (size_t)nr * W2;
#pragma unroll 2
  for (int j = tid; j < W2; j += NT) {
    float acc = 0.0f;
#pragma unroll
    for (int k = 0; k < 12; k++)
      acc += c_pkva[k] * xe[(j - 6 + k + W2) & (W2 - 1)];
    float dv = sgn * (xo[j] - acc);
    db[j] = dv;
    outd[j] = dv;
  }
  __syncthreads();
#pragma unroll 2
  for (int j = tid; j < W2; j += NT) {
    float acc = 0.0f;
#pragma unroll
    for (int k = 0; k < 12; k++)
      acc += c_pkva[k] * db[(j - 6 + k + W2) & (W2 - 1)];
    outs[j] = sgn * xe[j] + 0.5f * acc;
  }
}

// Batched square transpose (per-image), complex
__global__ void transpose_k(const float2* __restrict__ in,
                            float2* __restrict__ out, int N) {
  __shared__ float2 tile[32][33];
  int img = blockIdx.z;
  size_t base = (size_t)img * N * N;
  int x = blockIdx.x * 32 + threadIdx.x;
  int y0 = blockIdx.y * 32;
  for (int j = threadIdx.y; j < 32; j += 8)
    tile[j][threadIdx.x] = in[base + (size_t)(y0 + j) * N + x];
  __syncthreads();
  int x2 = blockIdx.y * 32 + threadIdx.x;
  int y2 = blockIdx.x * 32;
  for (int j = threadIdx.y; j < 32; j += 8)
    out[base + (size_t)(y2 + j) * N + x2] = tile[threadIdx.x][j];
}

// Frequency-domain decimation by 2 with Lm mask (level 3), table-driven.
__global__ void alias_k(const float2* __restrict__ in, float2* __restrict__ out,
                        int N, int lgN2, int phiOff) {
  int idx = blockIdx.x * 256 + threadIdx.x;
  int N2 = N >> 1;
  int c = idx & (N2 - 1);
  int r = (idx >> lgN2) & (N2 - 1);
  int img = idx >> (2 * lgN2);
  float pr0 = g_phi[phiOff + r], pr1 = g_phi[phiOff + r + N2];
  float pc0 = g_phi[phiOff + c], pc1 = g_phi[phiOff + c + N2];
  size_t base = (size_t)img * N * N;
  float2 v00 = in[base + (size_t)r * N + c];
  float2 v01 = in[base + (size_t)r * N + c + N2];
  float2 v10 = in[base + (size_t)(r + N2) * N + c];
  float2 v11 = in[base + (size_t)(r + N2) * N + c + N2];
  float m00 = pr0 * pc0, m01 = pr0 * pc1, m10 = pr1 * pc0, m11 = pr1 * pc1;
  float2 o;
  o.x = 0.25f * (v00.x * m00 + v01.x * m01 + v10.x * m10 + v11.x * m11);
  o.y = 0.25f * (v00.y * m00 + v01.y * m01 + v10.y * m10 + v11.y * m11);
  out[((size_t)img << (2 * lgN2)) + ((size_t)r << lgN2) + c] = o;
}

// Standalone DFB fan split, axis=-1 (mid-pipeline; W <= 512 here).
__global__ void __launch_bounds__(256)
fs_row_k(const float* __restrict__ x, float* __restrict__ outb,
         int lgH, int lgW, int halfT) {
  __shared__ float xe[512], xo[512], db[512];
  int H = 1 << lgH, W = 1 << lgW, W2 = W >> 1;
  int nr = blockIdx.x;
  int r = nr & (H - 1);
  int par = r & 1;
  float sgn = par ? -1.0f : 1.0f;
  const float* xrow = x + (size_t)nr * W;
  for (int j = threadIdx.x; j < W2; j += 256) {
    xe[j] = sgn * xrow[(2 * j + par) & (W - 1)];
    xo[j] = sgn * xrow[(2 * j + 1 + par) & (W - 1)];
  }
  __syncthreads();
  float* outs = outb + (size_t)nr * W2;
  float* outd = outb + halfT + (size_t)nr * W2;
  for (int j = threadIdx.x; j < W2; j += 256) {
    float acc = 0.0f;
#pragma unroll
    for (int k = 0; k < 12; k++)
      acc += c_pkva[k] * xe[(j - 6 + k + W2) & (W2 - 1)];
    float dv = xo[j] - acc;
    db[j] = dv;
    outd[j] = dv;
  }
  __syncthreads();
  for (int j = threadIdx.x; j < W2; j += 256) {
    float acc = 0.0f;
#pragma unroll
    for (int k = 0; k < 12; k++)
      acc += c_pkva[k] * db[(j - 6 + k + W2) & (W2 - 1)];
    outs[j] = xe[j] + 0.5f * acc;
  }
}

// ---------------------------------------------------------------------------
// FUSED column fan split (d AND s in one pass, input read once).
// ---------------------------------------------------------------------------
template <int TI, int TC>
__global__ void __launch_bounds__(256)
fs_col_fused_k(const float* __restrict__ x, float* __restrict__ outb,
               int lgH, int lgW, int halfT) {
  constexpr int RE = 2 * TI + 48;
  constexpr int DE = TI + 12;
  constexpr int NR = 256 / TC;
  __shared__ float raw[RE][TC];
  __shared__ float dvs[DE][TC];
  const int H = 1 << lgH, W = 1 << lgW;
  const int c0 = blockIdx.x * TC;
  const int i0 = blockIdx.y * TI;
  const int n = blockIdx.z;
  const int tc = threadIdx.x & (TC - 1);
  const int tr = threadIdx.x / TC;
  const float* xim = x + ((size_t)n << (lgH + lgW));
  const int rbase = 2 * i0 - 24;
#pragma unroll
  for (int r = tr; r < RE; r += NR) {
    int rr = (rbase + r) & (H - 1);
    raw[r][tc] = xim[((size_t)rr << lgW) + c0 + tc];
  }
  __syncthreads();
  const int par = tc & 1;
  for (int j = tr; j < DE; j += NR) {
    float acc = 0.0f;
#pragma unroll
    for (int k = 0; k < 12; k++)
      acc += c_pkva[k] * raw[2 * j + 2 * k + par][tc];
    dvs[j][tc] = raw[2 * j + 13 + par][tc] - acc;
  }
  __syncthreads();
  const float sgn = par ? -1.0f : 1.0f;
  float* outs = outb + (((size_t)n << (lgH - 1)) << lgW);
  float* outd = outs + halfT;
  for (int i = tr; i < TI; i += NR) {
    float acc = 0.0f;
#pragma unroll
    for (int k = 0; k < 12; k++)
      acc += c_pkva[k] * dvs[i + k][tc];
    float p0v = raw[2 * i + 24 + par][tc];
    size_t off = ((size_t)(i0 + i) << lgW) + c0 + tc;
    outd[off] = sgn * dvs[i + 6][tc];
    outs[off] = sgn * (p0v + 0.5f * acc);
  }
}

__global__ void fill_err_k(float* out) {
  out[threadIdx.x] = 1.0e9f;
}

// ---------------------------------------------------------------------------
extern "C" void kernel_launch(void* const* d_in, const int* in_sizes, int n_in,
                              void* d_out, int out_size, void* d_ws, size_t ws_size,
                              hipStream_t stream) {
  const float* x = (const float*)d_in[0];
  float* out = (float*)d_out;
  char* ws = (char*)d_ws;

  const size_t NEED = 220266496ull;
  if (ws_size < NEED) {
    fill_err_k<<<dim3(1), dim3(256), 0, stream>>>(out);
    return;
  }

  float2* bufA  = (float2*)(ws);                 // 16*1024*544*8 = 71303168
  float2* bufB  = (float2*)(ws + 71303168);      // 71303168
  float2* foldb = (float2*)(ws + 142606336);     // 16*513*512*8 = 33619968
  float2* spec2 = (float2*)(ws + 176226304);     // 33554432
  float2* spec3 = (float2*)(ws + 209780736);     // 8388608
  float2* spec4 = (float2*)(ws + 218169344);     // 2097152

  float* out0 = out;             // 262144
  float* out1 = out + 262144;    // 1048576
  float* out2 = out + 1310720;   // 4194304
  float* out3 = out + 5505024;   // 16777216

  phi_init_k<<<dim3(8), dim3(256), 0, stream>>>();

  // ---- Level 1 (half-spectrum in kx)
  // row rFFT written directly column-major [img][kx][y] (kills transpose #1)
  rfft_pairs_cm_k<1024, 544><<<dim3(8192), dim3(256), 0, stream>>>(x, bufB);
  fft_col_half_k<1024, 544><<<dim3(513, 16), dim3(256), 0, stream>>>(bufB, foldb);
  // kx-fold -> spec2 AND level-2 alias -> spec3 in one pass
  fold_alias_k<<<dim3(256, 16), dim3(256), 0, stream>>>(foldb, spec2, spec3);
  // bufB [img][kx](544 x 1024) -> bufA [img][y][kx](1024 x 544)
  transpose_rect_k<<<dim3(32, 17, 16), dim3(32, 8), 0, stream>>>(bufB, bufA, 544, 1024);
  ifft_fan_pair_k<1024, 544><<<dim3(8192), dim3(256), 0, stream>>>(bufA, (float*)bufB, 1.0f / 1024.0f, 8388608);
  // DFB n=4 remaining stages (fused column splits)
  fs_col_fused_k<64, 32><<<dim3(16, 8, 32), dim3(256), 0, stream>>>((float*)bufB, (float*)bufA, 10, 9, 8388608);
  fs_row_k<<<dim3(32768), dim3(256), 0, stream>>>((float*)bufA, (float*)bufB, 9, 9, 8388608);
  fs_col_fused_k<64, 32><<<dim3(8, 4, 128), dim3(256), 0, stream>>>((float*)bufB, out3, 9, 8, 8388608);

  // ---- Level 2 (spec3 already produced by fold_alias_k)
  fft_rows_k<512, 2, 0><<<dim3(8192), dim3(128), 0, stream>>>((const void*)spec2, (void*)bufA, 1.0f, 1.0f / 512.0f);
  transpose_k<<<dim3(16, 16, 16), dim3(32, 8), 0, stream>>>(bufA, bufB, 512);
  ifft_fan_k<512><<<dim3(8192), dim3(128), 0, stream>>>(bufB, (float*)bufA, 1.0f / 512.0f, 2097152);
  fs_col_fused_k<64, 32><<<dim3(8, 4, 32), dim3(256), 0, stream>>>((float*)bufA, (float*)bufB, 9, 8, 2097152);
  fs_row_k<<<dim3(16384), dim3(256), 0, stream>>>((float*)bufB, out2, 8, 8, 2097152);

  // ---- Level 3
  alias_k<<<dim3(1024), dim3(256), 0, stream>>>(spec3, spec4, 256, 7, phi_off(256));
  fft_rows_k<256, 2, 0><<<dim3(4096), dim3(64), 0, stream>>>((const void*)spec3, (void*)bufA, 1.0f, 1.0f / 256.0f);
  transpose_k<<<dim3(8, 8, 16), dim3(32, 8), 0, stream>>>(bufA, bufB, 256);
  ifft_fan_k<256><<<dim3(4096), dim3(64), 0, stream>>>(bufB, (float*)bufA, 1.0f / 256.0f, 524288);
  fs_col_fused_k<64, 32><<<dim3(4, 2, 32), dim3(256), 0, stream>>>((float*)bufA, out1, 8, 7, 524288);

  // ---- Final lowpass: out0 = ifft2(X4^T) at 128^2
  fft_rows_k<128, 1, 0><<<dim3(2048), dim3(32), 0, stream>>>((const void*)spec4, (void*)bufA, 1.0f, 1.0f / 128.0f);
  transpose_k<<<dim3(4, 4, 16), dim3(32, 8), 0, stream>>>(bufA, bufB, 128);
  fft_rows_k<128, 1, 1><<<dim3(2048), dim3(32), 0, stream>>>((const void*)bufB, (void*)out0, 1.0f, 1.0f / 128.0f);
}